// Round 14
// baseline (237.012 us; speedup 1.0000x reference)
//
#include <hip/hip_runtime.h>
#include <hip/hip_fp16.h>

#define BS 256
#define BSHIFT 9                // 512 nodes per bucket
#define BNODES (1 << BSHIFT)
#define NBKT 256                // bucket table size (>= ceil(100000/512)=196); n <= 2^17
#define CAP 12288               // edge capacity per bucket (mean 8192 at E=1.6M, +45 sigma)
#define CHUNK 4096              // edges per scatter chunk (16/thread)
#define NRNG 8                  // src ranges per node row (src>>14; 2MB of h1 per range)
// packed edge word: src in bits [0,17), local dst (li) in bits [17,26)

typedef _Float16 f16x8 __attribute__((ext_vector_type(8)));
typedef float f32x4 __attribute__((ext_vector_type(4)));

// ---------------- scatter: bin edges into fixed-capacity buckets ----------------

__global__ __launch_bounds__(BS) void k_scatter(const int* __restrict__ src,
                                                const int* __restrict__ dst,
                                                int* __restrict__ gcursor,
                                                int* __restrict__ binned, int E) {
    __shared__ int sh[NBKT];
    __shared__ int sbase[NBKT];
    int t = threadIdx.x;
    sh[t] = 0;
    __syncthreads();
    int cbase = blockIdx.x * CHUNK;
    int sv[CHUNK / BS], dv[CHUNK / BS], rv[CHUNK / BS];
#pragma unroll
    for (int j = 0; j < CHUNK / BS; ++j) {
        int e = cbase + j * BS + t;
        rv[j] = -1;
        if (e < E) {
            sv[j] = src[e];
            dv[j] = dst[e];
            rv[j] = atomicAdd(&sh[dv[j] >> BSHIFT], 1);
        }
    }
    __syncthreads();
    sbase[t] = sh[t] ? atomicAdd(&gcursor[t], sh[t]) : 0;
    __syncthreads();
#pragma unroll
    for (int j = 0; j < CHUNK / BS; ++j) {
        if (rv[j] >= 0) {
            int b = dv[j] >> BSHIFT;
            binned[(size_t)b * CAP + sbase[b] + rv[j]] =
                sv[j] | ((dv[j] & (BNODES - 1)) << 17);
        }
    }
}

// ---------------- build: (node,src-range) histogram -> scan -> range-ordered CSR ----
// Rows laid out [self | rng0 edges | rng1 | ... | rng7] so the agg kernels (unchanged)
// sweep h1 in ~2MB src-windows device-wide (L2 locality; r13 showed 38% L2 miss).

__global__ __launch_bounds__(BS) void k_build(const int* __restrict__ binned,
                                              const int* __restrict__ cnts,
                                              int2* __restrict__ rowptr2,
                                              float* __restrict__ dinv,
                                              int* __restrict__ csr, int n) {
    __shared__ int hb[BNODES * NRNG];   // 16 KB: histogram, then per-bin base
    __shared__ int cur[BNODES * NRNG];  // 16 KB
    __shared__ int ws[4];
    int t = threadIdx.x;
    int bkt = blockIdx.x;
    int node0 = bkt << BSHIFT;
    int nn = min(BNODES, n - node0);
    for (int i = t; i < BNODES * NRNG; i += BS) { hb[i] = 0; cur[i] = 0; }
    __syncthreads();
    int cnt = cnts[bkt];
    const int* eb = binned + (size_t)bkt * CAP;
    for (int e = t; e < cnt; e += BS) {
        int p = eb[e];
        atomicAdd(&hb[(p >> 17) * NRNG + ((p & 0x1FFFF) >> 14)], 1);
    }
    __syncthreads();
    // each thread owns 16 bins = nodes 2t, 2t+1
    int pre[17];
    pre[0] = 0;
#pragma unroll
    for (int j = 0; j < 16; ++j) pre[j + 1] = pre[j] + hb[16 * t + j];
    int tot = pre[16];
    int lane = t & 63, w = t >> 6;
    int incl = tot;
#pragma unroll
    for (int off = 1; off < 64; off <<= 1) {
        int u = __shfl_up(incl, off);
        if (lane >= off) incl += u;
    }
    if (lane == 63) ws[w] = incl;
    __syncthreads();
    int woff = 0;
    for (int q = 0; q < w; ++q) woff += ws[q];
    int texcl = woff + incl - tot;
    int i0 = 2 * t;
    int cb = bkt * (CAP + BNODES);
    int v0 = pre[8], v1 = tot - pre[8];
    int rA = cb + texcl + i0;                // row A start (self-loop slot)
    int rB = rA + v0 + 1;                    // row B start
    // overwrite own bins with absolute base addresses (no cross-thread access)
#pragma unroll
    for (int j = 0; j < 8; ++j) hb[16 * t + j] = rA + 1 + pre[j];
#pragma unroll
    for (int j = 8; j < 16; ++j) hb[16 * t + j] = rB + 1 + (pre[j] - pre[8]);
    if (i0 < nn) {
        rowptr2[node0 + i0] = make_int2(rA, rA + v0 + 1);
        dinv[node0 + i0] = rsqrtf((float)(v0 + 1));
        csr[rA] = node0 + i0;
    }
    if (i0 + 1 < nn) {
        rowptr2[node0 + i0 + 1] = make_int2(rB, rB + v1 + 1);
        dinv[node0 + i0 + 1] = rsqrtf((float)(v1 + 1));
        csr[rB] = node0 + i0 + 1;
    }
    __syncthreads();
    for (int e = t; e < cnt; e += BS) {
        int p = eb[e];
        int src = p & 0x1FFFF;
        int bin = (p >> 17) * NRNG + (src >> 14);
        int r = atomicAdd(&cur[bin], 1);
        csr[hb[bin] + r] = src;
    }
}

// ---------------- mgemm1: h1 = fp16(dinv .* (x @ W1)) ----------------
// A direct global->VGPR, W^T in LDS. Layouts verified r5.

__global__ __launch_bounds__(BS, 4) void k_mgemm1(const float* __restrict__ X,
                                                  const float* __restrict__ W,
                                                  const float* __restrict__ dscale,
                                                  __half* __restrict__ H, int n) {
    constexpr int K = 128, COLS = 64;
    constexpr int KC = K / 8;
    constexpr int SWZ = 15;
    constexpr int NT = COLS / 16;
    __shared__ __align__(16) _Float16 sB[COLS * K];
    int tid = threadIdx.x;
    for (int idx = tid; idx < COLS * KC; idx += BS) {
        int c = idx / KC, k8 = idx % KC;
        f16x8 v;
#pragma unroll
        for (int j = 0; j < 8; ++j) v[j] = (_Float16)W[(k8 * 8 + j) * COLS + c];
        *(f16x8*)&sB[c * K + ((k8 ^ (c & SWZ)) * 8)] = v;
    }
    __syncthreads();
    int w = tid >> 6, lane = tid & 63;
    int lm = lane & 15, q = lane >> 4;
    int row_m0 = blockIdx.x * 128 + w * 32;
    f32x4 acc[2][NT];
#pragma unroll
    for (int tm = 0; tm < 2; ++tm)
#pragma unroll
        for (int tn = 0; tn < NT; ++tn) acc[tm][tn] = (f32x4){0.f, 0.f, 0.f, 0.f};
#pragma unroll
    for (int kk = 0; kk < K / 32; ++kk) {
        int k0 = kk * 32 + q * 8;
        f16x8 af[2], bf[NT];
#pragma unroll
        for (int tm = 0; tm < 2; ++tm) {
            int row = row_m0 + tm * 16 + lm;
            int rl = row < n ? row : (n - 1);  // clamp: in-bounds, values unused
            const float4* xp = (const float4*)X + ((size_t)rl * K + k0) / 4;
            float4 a = xp[0], b = xp[1];
            f16x8 v;
            v[0] = (_Float16)a.x; v[1] = (_Float16)a.y;
            v[2] = (_Float16)a.z; v[3] = (_Float16)a.w;
            v[4] = (_Float16)b.x; v[5] = (_Float16)b.y;
            v[6] = (_Float16)b.z; v[7] = (_Float16)b.w;
            af[tm] = v;
        }
#pragma unroll
        for (int tn = 0; tn < NT; ++tn) {
            int c = tn * 16 + lm;
            bf[tn] = *(const f16x8*)&sB[c * K + (((kk * 4 + q) ^ (c & SWZ)) * 8)];
        }
#pragma unroll
        for (int tm = 0; tm < 2; ++tm)
#pragma unroll
            for (int tn = 0; tn < NT; ++tn)
                acc[tm][tn] = __builtin_amdgcn_mfma_f32_16x16x32_f16(af[tm], bf[tn],
                                                                     acc[tm][tn], 0, 0, 0);
    }
#pragma unroll
    for (int tm = 0; tm < 2; ++tm) {
#pragma unroll
        for (int r = 0; r < 4; ++r) {
            int row = row_m0 + tm * 16 + q * 4 + r;
            if (row < n) {
                float dv = dscale[row];
#pragma unroll
                for (int tn = 0; tn < NT; ++tn) {
                    int col = tn * 16 + lm;
                    H[(size_t)row * COLS + col] = __float2half_rn(acc[tm][tn][r] * dv);
                }
            }
        }
    }
}

// ---------------- aggmm: fused agg64 + relu(v+b1) + (u @ W2) * dinv -> h2 fp16 ------
// (unchanged from r13; row-internal edge order is invisible here)

__device__ __forceinline__ void acc_pk(float4 raw, __half2& p0, __half2& p1,
                                       __half2& p2, __half2& p3) {
    const __half2* u = (const __half2*)&raw;
    p0 = __hadd2(p0, u[0]); p1 = __hadd2(p1, u[1]);
    p2 = __hadd2(p2, u[2]); p3 = __hadd2(p3, u[3]);
}

__global__ __launch_bounds__(BS) void k_aggmm(const __half* __restrict__ h,
                                              const int* __restrict__ csr,
                                              const int2* __restrict__ rowptr2,
                                              const float* __restrict__ dinv,
                                              const float* __restrict__ b1,
                                              const float* __restrict__ W2,  // [64][32]
                                              __half* __restrict__ h2, int n) {
    __shared__ float sW2[64 * 32];            // 8 KB, layout [k][c]
    __shared__ float sB1[64];
    __shared__ float sU[(BS / 64) * 2 * 64];  // 4 waves x 2 nodes x 64 = 2 KB
    int t = threadIdx.x;
    for (int i = t; i < 64 * 32; i += BS) sW2[i] = W2[i];
    if (t < 64) sB1[t] = b1[t];
    __syncthreads();

    int npairs = (n + 1) / 2;
    int wib = t >> 6;
    int wid = blockIdx.x * (BS / 64) + wib;
    if (wid >= npairs) return;  // wave-uniform; no barriers after this point
    int lane = t & 63;
    int half = lane >> 5, hl = lane & 31;
    int node = wid * 2 + half;
    bool valid = node < n;
    int b = 0, e = 0;
    if (valid) { int2 be = rowptr2[node]; b = be.x; e = be.y; }
    int slot = hl >> 3, fq = hl & 7;  // 4 edge slots, feature octet fq*8..fq*8+8
    __half2 pA0 = __float2half2_rn(0.f), pA1 = pA0, pA2 = pA0, pA3 = pA0;
    __half2 pB0 = pA0, pB1 = pA0, pB2 = pA0, pB3 = pA0;
    for (int c = b; c < e; c += 32) {
        int m = e - c;
        if (m > 32) m = 32;
        int sv = (hl < m) ? csr[c + hl] : 0;
        int j = 0;
        for (; j + 7 < m; j += 8) {
            int s0 = __shfl(sv, j + slot, 32);
            int s1 = __shfl(sv, j + 4 + slot, 32);
            float4 r0 = *((const float4*)(h + (size_t)s0 * 64) + fq);
            float4 r1 = *((const float4*)(h + (size_t)s1 * 64) + fq);
            acc_pk(r0, pA0, pA1, pA2, pA3);
            acc_pk(r1, pB0, pB1, pB2, pB3);
        }
        for (; j < m; j += 4) {
            int js = j + slot;
            int s = __shfl(sv, js < m ? js : 0, 32);
            if (js < m) {
                float4 r0 = *((const float4*)(h + (size_t)s * 64) + fq);
                acc_pk(r0, pA0, pA1, pA2, pA3);
            }
        }
    }
    // merge packed partials in fp32: 8 feature sums per lane
    float2 f0 = __half22float2(pA0), f1 = __half22float2(pA1);
    float2 f2 = __half22float2(pA2), f3 = __half22float2(pA3);
    float2 g0 = __half22float2(pB0), g1v = __half22float2(pB1);
    float2 g2 = __half22float2(pB2), g3 = __half22float2(pB3);
    float a0 = f0.x + g0.x, a1 = f0.y + g0.y, a2 = f1.x + g1v.x, a3 = f1.y + g1v.y;
    float a4 = f2.x + g2.x, a5 = f2.y + g2.y, a6 = f3.x + g3.x, a7 = f3.y + g3.y;
    // cross-slot reduction: slots {0,1,2,3} at hl = slot*8+fq
    a0 += __shfl_down(a0, 16); a1 += __shfl_down(a1, 16);
    a2 += __shfl_down(a2, 16); a3 += __shfl_down(a3, 16);
    a4 += __shfl_down(a4, 16); a5 += __shfl_down(a5, 16);
    a6 += __shfl_down(a6, 16); a7 += __shfl_down(a7, 16);
    a0 += __shfl_down(a0, 8);  a1 += __shfl_down(a1, 8);
    a2 += __shfl_down(a2, 8);  a3 += __shfl_down(a3, 8);
    a4 += __shfl_down(a4, 8);  a5 += __shfl_down(a5, 8);
    a6 += __shfl_down(a6, 8);  a7 += __shfl_down(a7, 8);

    // layer-2 input: u = relu(dinv[node] * acc + b1); lanes hl<8 own features hl*8..+8
    if (valid && hl < 8) {
        float dv = dinv[node];
        float* up = &sU[(wib * 2 + half) * 64 + hl * 8];
        up[0] = fmaxf(a0 * dv + sB1[hl * 8 + 0], 0.f);
        up[1] = fmaxf(a1 * dv + sB1[hl * 8 + 1], 0.f);
        up[2] = fmaxf(a2 * dv + sB1[hl * 8 + 2], 0.f);
        up[3] = fmaxf(a3 * dv + sB1[hl * 8 + 3], 0.f);
        up[4] = fmaxf(a4 * dv + sB1[hl * 8 + 4], 0.f);
        up[5] = fmaxf(a5 * dv + sB1[hl * 8 + 5], 0.f);
        up[6] = fmaxf(a6 * dv + sB1[hl * 8 + 6], 0.f);
        up[7] = fmaxf(a7 * dv + sB1[hl * 8 + 7], 0.f);
    }
    // in-wave matvec: lanes 0-31 -> node A cols, lanes 32-63 -> node B cols.
    int nodeSel = lane >> 5;
    int mvnode = wid * 2 + nodeSel;
    if (mvnode < n) {
        const float* u = &sU[(wib * 2 + nodeSel) * 64];
        int cc = lane & 31;
        float acc = 0.f;
#pragma unroll
        for (int k = 0; k < 64; ++k) acc = fmaf(u[k], sW2[k * 32 + cc], acc);
        h2[(size_t)mvnode * 32 + cc] = __float2half_rn(acc * dinv[mvnode]);
    }
}

// ---------------- agg32: out = dinv .* (A-gather h2) + b2 (fp32) ----------------
// (unchanged from r13)

__global__ __launch_bounds__(BS) void k_agg32(const __half* __restrict__ h,
                                              const int* __restrict__ csr,
                                              const int2* __restrict__ rowptr2,
                                              const float* __restrict__ dinv,
                                              const float* __restrict__ bias,
                                              float* __restrict__ out, int n) {
    int wid = (blockIdx.x * BS + threadIdx.x) >> 6;
    int lane = threadIdx.x & 63;
    int half = lane >> 5, hl = lane & 31;
    int node = wid * 2 + half;
    bool valid = node < n;
    int b = 0, e = 0;
    if (valid) { int2 be = rowptr2[node]; b = be.x; e = be.y; }
    int slot = hl >> 2, fq = hl & 3;  // 8 edge slots, feature octet fq*8..fq*8+8
    float a0 = 0.f, a1 = 0.f, a2 = 0.f, a3 = 0.f;
    float a4 = 0.f, a5 = 0.f, a6 = 0.f, a7 = 0.f;
    for (int c = b; c < e; c += 32) {
        int m = e - c;
        if (m > 32) m = 32;
        int sv = (hl < m) ? csr[c + hl] : 0;
        int j = 0;
        for (; j + 15 < m; j += 16) {
            int s0 = __shfl(sv, j + slot, 32);
            int s1 = __shfl(sv, j + 8 + slot, 32);
            float4 r0 = *((const float4*)(h + (size_t)s0 * 32) + fq);
            float4 r1 = *((const float4*)(h + (size_t)s1 * 32) + fq);
            const __half2* u0 = (const __half2*)&r0;
            const __half2* u1 = (const __half2*)&r1;
            float2 q0 = __half22float2(u0[0]), q1 = __half22float2(u0[1]);
            float2 q2 = __half22float2(u0[2]), q3 = __half22float2(u0[3]);
            a0 += q0.x; a1 += q0.y; a2 += q1.x; a3 += q1.y;
            a4 += q2.x; a5 += q2.y; a6 += q3.x; a7 += q3.y;
            q0 = __half22float2(u1[0]); q1 = __half22float2(u1[1]);
            q2 = __half22float2(u1[2]); q3 = __half22float2(u1[3]);
            a0 += q0.x; a1 += q0.y; a2 += q1.x; a3 += q1.y;
            a4 += q2.x; a5 += q2.y; a6 += q3.x; a7 += q3.y;
        }
        for (; j < m; j += 8) {
            int js = j + slot;
            int s = __shfl(sv, js < m ? js : 0, 32);
            if (js < m) {
                float4 r0 = *((const float4*)(h + (size_t)s * 32) + fq);
                const __half2* u0 = (const __half2*)&r0;
                float2 q0 = __half22float2(u0[0]), q1 = __half22float2(u0[1]);
                float2 q2 = __half22float2(u0[2]), q3 = __half22float2(u0[3]);
                a0 += q0.x; a1 += q0.y; a2 += q1.x; a3 += q1.y;
                a4 += q2.x; a5 += q2.y; a6 += q3.x; a7 += q3.y;
            }
        }
    }
    // cross-slot reduction: slots {0..7} at hl = slot*4+fq
    a0 += __shfl_down(a0, 16); a1 += __shfl_down(a1, 16);
    a2 += __shfl_down(a2, 16); a3 += __shfl_down(a3, 16);
    a4 += __shfl_down(a4, 16); a5 += __shfl_down(a5, 16);
    a6 += __shfl_down(a6, 16); a7 += __shfl_down(a7, 16);
    a0 += __shfl_down(a0, 8);  a1 += __shfl_down(a1, 8);
    a2 += __shfl_down(a2, 8);  a3 += __shfl_down(a3, 8);
    a4 += __shfl_down(a4, 8);  a5 += __shfl_down(a5, 8);
    a6 += __shfl_down(a6, 8);  a7 += __shfl_down(a7, 8);
    a0 += __shfl_down(a0, 4);  a1 += __shfl_down(a1, 4);
    a2 += __shfl_down(a2, 4);  a3 += __shfl_down(a3, 4);
    a4 += __shfl_down(a4, 4);  a5 += __shfl_down(a5, 4);
    a6 += __shfl_down(a6, 4);  a7 += __shfl_down(a7, 4);
    if (valid && hl < 4) {
        float dv = dinv[node];
        const float4* bp = (const float4*)bias + hl * 2;
        float4 b0 = bp[0], b1v = bp[1];
        float4 o0 = make_float4(a0 * dv + b0.x, a1 * dv + b0.y,
                                a2 * dv + b0.z, a3 * dv + b0.w);
        float4 o1 = make_float4(a4 * dv + b1v.x, a5 * dv + b1v.y,
                                a6 * dv + b1v.z, a7 * dv + b1v.w);
        float4* op = (float4*)(out + (size_t)node * 32 + hl * 8);
        op[0] = o0; op[1] = o1;
    }
}

// ---------------- launch ----------------

extern "C" void kernel_launch(void* const* d_in, const int* in_sizes, int n_in,
                              void* d_out, int out_size, void* d_ws, size_t ws_size,
                              hipStream_t stream) {
    const float* x  = (const float*)d_in[0];
    const int* eidx = (const int*)d_in[1];
    const float* W1 = (const float*)d_in[2];
    const float* b1 = (const float*)d_in[3];
    const float* W2 = (const float*)d_in[4];
    const float* b2 = (const float*)d_in[5];
    float* out = (float*)d_out;

    int n = in_sizes[0] / 128;
    int E = in_sizes[1] / 2;
    const int* srcA = eidx;
    const int* dstA = eidx + E;

    char* p = (char*)d_ws;
    auto alloc = [&](size_t bytes) {
        char* q = p;
        p += (bytes + 255) & ~(size_t)255;
        return q;
    };
    int2*   rowptr2 = (int2*)alloc((size_t)n * 8);
    float*  dinv    = (float*)alloc((size_t)n * 4);
    int*    gcursor = (int*)alloc(NBKT * 4);
    int*    binned  = (int*)alloc((size_t)NBKT * CAP * 4);
    int*    csr     = (int*)alloc((size_t)NBKT * (CAP + BNODES) * 4);
    __half* h1      = (__half*)alloc((size_t)n * 64 * 2);
    __half* h2      = (__half*)alloc((size_t)n * 32 * 2);

    int nchunks  = (E + CHUNK - 1) / CHUNK;           // 391
    int nbuckets = (n + BNODES - 1) / BNODES;         // 196 (<= NBKT)
    int nblk     = (n + 127) / 128;                   // 782
    int npairs   = (n + 1) / 2;                       // 2 nodes per wave
    int aggblk   = (npairs + (BS / 64) - 1) / (BS / 64);

    hipMemsetAsync(gcursor, 0, NBKT * 4, stream);
    k_scatter<<<nchunks, BS, 0, stream>>>(srcA, dstA, gcursor, binned, E);
    k_build<<<nbuckets, BS, 0, stream>>>(binned, gcursor, rowptr2, dinv, csr, n);
    k_mgemm1<<<nblk, BS, 0, stream>>>(x, W1, dinv, h1, n);
    k_aggmm<<<aggblk, BS, 0, stream>>>(h1, csr, rowptr2, dinv, b1, W2, h2, n);
    k_agg32<<<aggblk, BS, 0, stream>>>(h2, csr, rowptr2, dinv, b2, out, n);
}

// Round 15
// 233.895 us; speedup vs baseline: 1.0133x; 1.0133x over previous
//
#include <hip/hip_runtime.h>
#include <hip/hip_fp16.h>

#define BS 256
#define BSHIFT 9                // 512 nodes per bucket
#define BNODES (1 << BSHIFT)
#define NBKT 256                // bucket table size (>= ceil(100000/512)=196); n <= 2^17
#define CAP 12288               // edge capacity per bucket (mean 8192 at E=1.6M, +45 sigma)
#define CHUNK 4096              // edges per scatter chunk (16/thread)
// packed edge word: src in bits [0,17), local dst (li) in bits [17,26)

typedef _Float16 f16x8 __attribute__((ext_vector_type(8)));
typedef float f32x4 __attribute__((ext_vector_type(4)));

// ---------------- scatter: bin edges into fixed-capacity buckets ----------------

__global__ __launch_bounds__(BS) void k_scatter(const int* __restrict__ src,
                                                const int* __restrict__ dst,
                                                int* __restrict__ gcursor,
                                                int* __restrict__ binned, int E) {
    __shared__ int sh[NBKT];
    __shared__ int sbase[NBKT];
    int t = threadIdx.x;
    sh[t] = 0;
    __syncthreads();
    int cbase = blockIdx.x * CHUNK;
    int sv[CHUNK / BS], dv[CHUNK / BS], rv[CHUNK / BS];
#pragma unroll
    for (int j = 0; j < CHUNK / BS; ++j) {
        int e = cbase + j * BS + t;
        rv[j] = -1;
        if (e < E) {
            sv[j] = src[e];
            dv[j] = dst[e];
            rv[j] = atomicAdd(&sh[dv[j] >> BSHIFT], 1);
        }
    }
    __syncthreads();
    sbase[t] = sh[t] ? atomicAdd(&gcursor[t], sh[t]) : 0;
    __syncthreads();
#pragma unroll
    for (int j = 0; j < CHUNK / BS; ++j) {
        if (rv[j] >= 0) {
            int b = dv[j] >> BSHIFT;
            binned[(size_t)b * CAP + sbase[b] + rv[j]] =
                sv[j] | ((dv[j] & (BNODES - 1)) << 17);
        }
    }
}

// ---------------- build: histogram -> LDS scan -> rowptr2/dinv -> bucket CSR ----------------

__global__ __launch_bounds__(BS) void k_build(const int* __restrict__ binned,
                                              const int* __restrict__ cnts,
                                              int2* __restrict__ rowptr2,
                                              float* __restrict__ dinv,
                                              int* __restrict__ csr, int n) {
    __shared__ int h[BNODES];
    __shared__ int rp[BNODES];
    __shared__ int cur[BNODES];
    __shared__ int ws[4];
    int t = threadIdx.x;
    int bkt = blockIdx.x;
    int node0 = bkt << BSHIFT;
    int nn = min(BNODES, n - node0);
#pragma unroll
    for (int i = t; i < BNODES; i += BS) h[i] = 0;
    __syncthreads();
    int cnt = cnts[bkt];
    const int* eb = binned + (size_t)bkt * CAP;
    for (int e = t; e < cnt; e += BS) atomicAdd(&h[eb[e] >> 17], 1);
    __syncthreads();
    int i0 = 2 * t;
    int v0 = h[i0], v1 = h[i0 + 1];
    int pair = v0 + v1;
    int lane = t & 63, w = t >> 6;
    int incl = pair;
#pragma unroll
    for (int off = 1; off < 64; off <<= 1) {
        int u = __shfl_up(incl, off);
        if (lane >= off) incl += u;
    }
    if (lane == 63) ws[w] = incl;
    __syncthreads();
    int woff = 0;
    for (int q = 0; q < w; ++q) woff += ws[q];
    int excl = woff + incl - pair;
    int cb = bkt * (CAP + BNODES);
    int r0 = cb + excl + i0;
    int r1 = r0 + v0 + 1;
    rp[i0] = r0; rp[i0 + 1] = r1;
    cur[i0] = 1; cur[i0 + 1] = 1;  // slot 0 = self-loop
    if (i0 < nn) {
        rowptr2[node0 + i0] = make_int2(r0, r1);
        dinv[node0 + i0] = rsqrtf((float)(v0 + 1));
        csr[r0] = node0 + i0;
    }
    if (i0 + 1 < nn) {
        rowptr2[node0 + i0 + 1] = make_int2(r1, r1 + v1 + 1);
        dinv[node0 + i0 + 1] = rsqrtf((float)(v1 + 1));
        csr[r1] = node0 + i0 + 1;
    }
    __syncthreads();
    for (int e = t; e < cnt; e += BS) {
        int p = eb[e];
        int li = p >> 17;
        int r = atomicAdd(&cur[li], 1);
        csr[rp[li] + r] = p & 0x1FFFF;
    }
}

// ---------------- mgemm1: h1 = fp16(dinv .* (x @ W1)) ----------------
// A direct global->VGPR, W^T in LDS. Layouts verified r5.

__global__ __launch_bounds__(BS, 4) void k_mgemm1(const float* __restrict__ X,
                                                  const float* __restrict__ W,
                                                  const float* __restrict__ dscale,
                                                  __half* __restrict__ H, int n) {
    constexpr int K = 128, COLS = 64;
    constexpr int KC = K / 8;
    constexpr int SWZ = 15;
    constexpr int NT = COLS / 16;
    __shared__ __align__(16) _Float16 sB[COLS * K];
    int tid = threadIdx.x;
    for (int idx = tid; idx < COLS * KC; idx += BS) {
        int c = idx / KC, k8 = idx % KC;
        f16x8 v;
#pragma unroll
        for (int j = 0; j < 8; ++j) v[j] = (_Float16)W[(k8 * 8 + j) * COLS + c];
        *(f16x8*)&sB[c * K + ((k8 ^ (c & SWZ)) * 8)] = v;
    }
    __syncthreads();
    int w = tid >> 6, lane = tid & 63;
    int lm = lane & 15, q = lane >> 4;
    int row_m0 = blockIdx.x * 128 + w * 32;
    f32x4 acc[2][NT];
#pragma unroll
    for (int tm = 0; tm < 2; ++tm)
#pragma unroll
        for (int tn = 0; tn < NT; ++tn) acc[tm][tn] = (f32x4){0.f, 0.f, 0.f, 0.f};
#pragma unroll
    for (int kk = 0; kk < K / 32; ++kk) {
        int k0 = kk * 32 + q * 8;
        f16x8 af[2], bf[NT];
#pragma unroll
        for (int tm = 0; tm < 2; ++tm) {
            int row = row_m0 + tm * 16 + lm;
            int rl = row < n ? row : (n - 1);  // clamp: in-bounds, values unused
            const float4* xp = (const float4*)X + ((size_t)rl * K + k0) / 4;
            float4 a = xp[0], b = xp[1];
            f16x8 v;
            v[0] = (_Float16)a.x; v[1] = (_Float16)a.y;
            v[2] = (_Float16)a.z; v[3] = (_Float16)a.w;
            v[4] = (_Float16)b.x; v[5] = (_Float16)b.y;
            v[6] = (_Float16)b.z; v[7] = (_Float16)b.w;
            af[tm] = v;
        }
#pragma unroll
        for (int tn = 0; tn < NT; ++tn) {
            int c = tn * 16 + lm;
            bf[tn] = *(const f16x8*)&sB[c * K + (((kk * 4 + q) ^ (c & SWZ)) * 8)];
        }
#pragma unroll
        for (int tm = 0; tm < 2; ++tm)
#pragma unroll
            for (int tn = 0; tn < NT; ++tn)
                acc[tm][tn] = __builtin_amdgcn_mfma_f32_16x16x32_f16(af[tm], bf[tn],
                                                                     acc[tm][tn], 0, 0, 0);
    }
#pragma unroll
    for (int tm = 0; tm < 2; ++tm) {
#pragma unroll
        for (int r = 0; r < 4; ++r) {
            int row = row_m0 + tm * 16 + q * 4 + r;
            if (row < n) {
                float dv = dscale[row];
#pragma unroll
                for (int tn = 0; tn < NT; ++tn) {
                    int col = tn * 16 + lm;
                    H[(size_t)row * COLS + col] = __float2half_rn(acc[tm][tn][r] * dv);
                }
            }
        }
    }
}

// ---------------- aggmm: fused agg64 + relu(v+b1) + (u @ W2) * dinv -> h2 fp16 ------
// Gather: 8 lanes/edge x float4, 4 edge slots per 32-lane half, 2-deep staging.
// Packed v_pk_add_f16 accumulation, merged in fp32 before the layer-2 matvec.
// Pinned at ~52us (memory-service bound): invariant under 2x concurrency (r9),
// 2.5x instruction cut (r13), and locality reordering (r14).

__device__ __forceinline__ void acc_pk(float4 raw, __half2& p0, __half2& p1,
                                       __half2& p2, __half2& p3) {
    const __half2* u = (const __half2*)&raw;
    p0 = __hadd2(p0, u[0]); p1 = __hadd2(p1, u[1]);
    p2 = __hadd2(p2, u[2]); p3 = __hadd2(p3, u[3]);
}

__global__ __launch_bounds__(BS) void k_aggmm(const __half* __restrict__ h,
                                              const int* __restrict__ csr,
                                              const int2* __restrict__ rowptr2,
                                              const float* __restrict__ dinv,
                                              const float* __restrict__ b1,
                                              const float* __restrict__ W2,  // [64][32]
                                              __half* __restrict__ h2, int n) {
    __shared__ float sW2[64 * 32];            // 8 KB, layout [k][c]
    __shared__ float sB1[64];
    __shared__ float sU[(BS / 64) * 2 * 64];  // 4 waves x 2 nodes x 64 = 2 KB
    int t = threadIdx.x;
    for (int i = t; i < 64 * 32; i += BS) sW2[i] = W2[i];
    if (t < 64) sB1[t] = b1[t];
    __syncthreads();

    int npairs = (n + 1) / 2;
    int wib = t >> 6;
    int wid = blockIdx.x * (BS / 64) + wib;
    if (wid >= npairs) return;  // wave-uniform; no barriers after this point
    int lane = t & 63;
    int half = lane >> 5, hl = lane & 31;
    int node = wid * 2 + half;
    bool valid = node < n;
    int b = 0, e = 0;
    if (valid) { int2 be = rowptr2[node]; b = be.x; e = be.y; }
    int slot = hl >> 3, fq = hl & 7;  // 4 edge slots, feature octet fq*8..fq*8+8
    __half2 pA0 = __float2half2_rn(0.f), pA1 = pA0, pA2 = pA0, pA3 = pA0;
    __half2 pB0 = pA0, pB1 = pA0, pB2 = pA0, pB3 = pA0;
    for (int c = b; c < e; c += 32) {
        int m = e - c;
        if (m > 32) m = 32;
        int sv = (hl < m) ? csr[c + hl] : 0;
        int j = 0;
        for (; j + 7 < m; j += 8) {
            int s0 = __shfl(sv, j + slot, 32);
            int s1 = __shfl(sv, j + 4 + slot, 32);
            float4 r0 = *((const float4*)(h + (size_t)s0 * 64) + fq);
            float4 r1 = *((const float4*)(h + (size_t)s1 * 64) + fq);
            acc_pk(r0, pA0, pA1, pA2, pA3);
            acc_pk(r1, pB0, pB1, pB2, pB3);
        }
        for (; j < m; j += 4) {
            int js = j + slot;
            int s = __shfl(sv, js < m ? js : 0, 32);
            if (js < m) {
                float4 r0 = *((const float4*)(h + (size_t)s * 64) + fq);
                acc_pk(r0, pA0, pA1, pA2, pA3);
            }
        }
    }
    // merge packed partials in fp32: 8 feature sums per lane
    float2 f0 = __half22float2(pA0), f1 = __half22float2(pA1);
    float2 f2 = __half22float2(pA2), f3 = __half22float2(pA3);
    float2 g0 = __half22float2(pB0), g1v = __half22float2(pB1);
    float2 g2 = __half22float2(pB2), g3 = __half22float2(pB3);
    float a0 = f0.x + g0.x, a1 = f0.y + g0.y, a2 = f1.x + g1v.x, a3 = f1.y + g1v.y;
    float a4 = f2.x + g2.x, a5 = f2.y + g2.y, a6 = f3.x + g3.x, a7 = f3.y + g3.y;
    // cross-slot reduction: slots {0,1,2,3} at hl = slot*8+fq
    a0 += __shfl_down(a0, 16); a1 += __shfl_down(a1, 16);
    a2 += __shfl_down(a2, 16); a3 += __shfl_down(a3, 16);
    a4 += __shfl_down(a4, 16); a5 += __shfl_down(a5, 16);
    a6 += __shfl_down(a6, 16); a7 += __shfl_down(a7, 16);
    a0 += __shfl_down(a0, 8);  a1 += __shfl_down(a1, 8);
    a2 += __shfl_down(a2, 8);  a3 += __shfl_down(a3, 8);
    a4 += __shfl_down(a4, 8);  a5 += __shfl_down(a5, 8);
    a6 += __shfl_down(a6, 8);  a7 += __shfl_down(a7, 8);

    // layer-2 input: u = relu(dinv[node] * acc + b1); lanes hl<8 own features hl*8..+8
    if (valid && hl < 8) {
        float dv = dinv[node];
        float* up = &sU[(wib * 2 + half) * 64 + hl * 8];
        up[0] = fmaxf(a0 * dv + sB1[hl * 8 + 0], 0.f);
        up[1] = fmaxf(a1 * dv + sB1[hl * 8 + 1], 0.f);
        up[2] = fmaxf(a2 * dv + sB1[hl * 8 + 2], 0.f);
        up[3] = fmaxf(a3 * dv + sB1[hl * 8 + 3], 0.f);
        up[4] = fmaxf(a4 * dv + sB1[hl * 8 + 4], 0.f);
        up[5] = fmaxf(a5 * dv + sB1[hl * 8 + 5], 0.f);
        up[6] = fmaxf(a6 * dv + sB1[hl * 8 + 6], 0.f);
        up[7] = fmaxf(a7 * dv + sB1[hl * 8 + 7], 0.f);
    }
    // in-wave matvec: lanes 0-31 -> node A cols, lanes 32-63 -> node B cols.
    int nodeSel = lane >> 5;
    int mvnode = wid * 2 + nodeSel;
    if (mvnode < n) {
        const float* u = &sU[(wib * 2 + nodeSel) * 64];
        int cc = lane & 31;
        float acc = 0.f;
#pragma unroll
        for (int k = 0; k < 64; ++k) acc = fmaf(u[k], sW2[k * 32 + cc], acc);
        h2[(size_t)mvnode * 32 + cc] = __float2half_rn(acc * dinv[mvnode]);
    }
}

// ---------------- agg32: out = dinv .* (A-gather h2) + b2 (fp32) ----------------
// 4 lanes/edge x float4 (full 64B row), 8 edge slots per half, fp32 accumulate.

__global__ __launch_bounds__(BS) void k_agg32(const __half* __restrict__ h,
                                              const int* __restrict__ csr,
                                              const int2* __restrict__ rowptr2,
                                              const float* __restrict__ dinv,
                                              const float* __restrict__ bias,
                                              float* __restrict__ out, int n) {
    int wid = (blockIdx.x * BS + threadIdx.x) >> 6;
    int lane = threadIdx.x & 63;
    int half = lane >> 5, hl = lane & 31;
    int node = wid * 2 + half;
    bool valid = node < n;
    int b = 0, e = 0;
    if (valid) { int2 be = rowptr2[node]; b = be.x; e = be.y; }
    int slot = hl >> 2, fq = hl & 3;  // 8 edge slots, feature octet fq*8..fq*8+8
    float a0 = 0.f, a1 = 0.f, a2 = 0.f, a3 = 0.f;
    float a4 = 0.f, a5 = 0.f, a6 = 0.f, a7 = 0.f;
    for (int c = b; c < e; c += 32) {
        int m = e - c;
        if (m > 32) m = 32;
        int sv = (hl < m) ? csr[c + hl] : 0;
        int j = 0;
        for (; j + 15 < m; j += 16) {
            int s0 = __shfl(sv, j + slot, 32);
            int s1 = __shfl(sv, j + 8 + slot, 32);
            float4 r0 = *((const float4*)(h + (size_t)s0 * 32) + fq);
            float4 r1 = *((const float4*)(h + (size_t)s1 * 32) + fq);
            const __half2* u0 = (const __half2*)&r0;
            const __half2* u1 = (const __half2*)&r1;
            float2 q0 = __half22float2(u0[0]), q1 = __half22float2(u0[1]);
            float2 q2 = __half22float2(u0[2]), q3 = __half22float2(u0[3]);
            a0 += q0.x; a1 += q0.y; a2 += q1.x; a3 += q1.y;
            a4 += q2.x; a5 += q2.y; a6 += q3.x; a7 += q3.y;
            q0 = __half22float2(u1[0]); q1 = __half22float2(u1[1]);
            q2 = __half22float2(u1[2]); q3 = __half22float2(u1[3]);
            a0 += q0.x; a1 += q0.y; a2 += q1.x; a3 += q1.y;
            a4 += q2.x; a5 += q2.y; a6 += q3.x; a7 += q3.y;
        }
        for (; j < m; j += 8) {
            int js = j + slot;
            int s = __shfl(sv, js < m ? js : 0, 32);
            if (js < m) {
                float4 r0 = *((const float4*)(h + (size_t)s * 32) + fq);
                const __half2* u0 = (const __half2*)&r0;
                float2 q0 = __half22float2(u0[0]), q1 = __half22float2(u0[1]);
                float2 q2 = __half22float2(u0[2]), q3 = __half22float2(u0[3]);
                a0 += q0.x; a1 += q0.y; a2 += q1.x; a3 += q1.y;
                a4 += q2.x; a5 += q2.y; a6 += q3.x; a7 += q3.y;
            }
        }
    }
    // cross-slot reduction: slots {0..7} at hl = slot*4+fq
    a0 += __shfl_down(a0, 16); a1 += __shfl_down(a1, 16);
    a2 += __shfl_down(a2, 16); a3 += __shfl_down(a3, 16);
    a4 += __shfl_down(a4, 16); a5 += __shfl_down(a5, 16);
    a6 += __shfl_down(a6, 16); a7 += __shfl_down(a7, 16);
    a0 += __shfl_down(a0, 8);  a1 += __shfl_down(a1, 8);
    a2 += __shfl_down(a2, 8);  a3 += __shfl_down(a3, 8);
    a4 += __shfl_down(a4, 8);  a5 += __shfl_down(a5, 8);
    a6 += __shfl_down(a6, 8);  a7 += __shfl_down(a7, 8);
    a0 += __shfl_down(a0, 4);  a1 += __shfl_down(a1, 4);
    a2 += __shfl_down(a2, 4);  a3 += __shfl_down(a3, 4);
    a4 += __shfl_down(a4, 4);  a5 += __shfl_down(a5, 4);
    a6 += __shfl_down(a6, 4);  a7 += __shfl_down(a7, 4);
    if (valid && hl < 4) {
        float dv = dinv[node];
        const float4* bp = (const float4*)bias + hl * 2;
        float4 b0 = bp[0], b1v = bp[1];
        float4 o0 = make_float4(a0 * dv + b0.x, a1 * dv + b0.y,
                                a2 * dv + b0.z, a3 * dv + b0.w);
        float4 o1 = make_float4(a4 * dv + b1v.x, a5 * dv + b1v.y,
                                a6 * dv + b1v.z, a7 * dv + b1v.w);
        float4* op = (float4*)(out + (size_t)node * 32 + hl * 8);
        op[0] = o0; op[1] = o1;
    }
}

// ---------------- launch ----------------

extern "C" void kernel_launch(void* const* d_in, const int* in_sizes, int n_in,
                              void* d_out, int out_size, void* d_ws, size_t ws_size,
                              hipStream_t stream) {
    const float* x  = (const float*)d_in[0];
    const int* eidx = (const int*)d_in[1];
    const float* W1 = (const float*)d_in[2];
    const float* b1 = (const float*)d_in[3];
    const float* W2 = (const float*)d_in[4];
    const float* b2 = (const float*)d_in[5];
    float* out = (float*)d_out;

    int n = in_sizes[0] / 128;
    int E = in_sizes[1] / 2;
    const int* srcA = eidx;
    const int* dstA = eidx + E;

    char* p = (char*)d_ws;
    auto alloc = [&](size_t bytes) {
        char* q = p;
        p += (bytes + 255) & ~(size_t)255;
        return q;
    };
    int2*   rowptr2 = (int2*)alloc((size_t)n * 8);
    float*  dinv    = (float*)alloc((size_t)n * 4);
    int*    gcursor = (int*)alloc(NBKT * 4);
    int*    binned  = (int*)alloc((size_t)NBKT * CAP * 4);
    int*    csr     = (int*)alloc((size_t)NBKT * (CAP + BNODES) * 4);
    __half* h1      = (__half*)alloc((size_t)n * 64 * 2);
    __half* h2      = (__half*)alloc((size_t)n * 32 * 2);

    int nchunks  = (E + CHUNK - 1) / CHUNK;           // 391
    int nbuckets = (n + BNODES - 1) / BNODES;         // 196 (<= NBKT)
    int nblk     = (n + 127) / 128;                   // 782
    int npairs   = (n + 1) / 2;                       // 2 nodes per wave
    int aggblk   = (npairs + (BS / 64) - 1) / (BS / 64);

    hipMemsetAsync(gcursor, 0, NBKT * 4, stream);
    k_scatter<<<nchunks, BS, 0, stream>>>(srcA, dstA, gcursor, binned, E);
    k_build<<<nbuckets, BS, 0, stream>>>(binned, gcursor, rowptr2, dinv, csr, n);
    k_mgemm1<<<nblk, BS, 0, stream>>>(x, W1, dinv, h1, n);
    k_aggmm<<<aggblk, BS, 0, stream>>>(h1, csr, rowptr2, dinv, b1, W2, h2, n);
    k_agg32<<<aggblk, BS, 0, stream>>>(h2, csr, rowptr2, dinv, b2, out, n);
}